// Round 8
// baseline (558.010 us; speedup 1.0000x reference)
//
#include <hip/hip_runtime.h>

#define N_NODES 50000
#define N_EDGES 800000
#define IN_DIM  162
#define HID     256
#define KPAD1   192   // IN_DIM padded to multiple of 32
#define NB      ((N_NODES + 255) / 256)   // 196 scan blocks

typedef __bf16 bf16;
typedef __bf16 bf16x8 __attribute__((ext_vector_type(8)));
typedef __bf16 bf16x4 __attribute__((ext_vector_type(4)));
typedef float  f32x4  __attribute__((ext_vector_type(4)));
typedef float  f32x8  __attribute__((ext_vector_type(8)));
typedef float  f32x16 __attribute__((ext_vector_type(16)));

#define GLDS16(g, l) __builtin_amdgcn_global_load_lds( \
    (const __attribute__((address_space(1))) void*)(g), \
    (__attribute__((address_space(3))) void*)(l), 16, 0, 0)

// ---------------------------------------------------------------------------
// All 4 weight transposes in one launch. W[K][HID] f32 -> Wt[HID][KPAD] bf16.
__device__ __forceinline__ void wt_one(const float* W, bf16* Wt, int K, int KPAD, int idx)
{
    int n = idx / KPAD;
    int k = idx - n * KPAD;
    Wt[idx] = (k < K) ? (bf16)W[(size_t)k * HID + n] : (bf16)0.0f;
}

__global__ void wt_transpose_all(const float* __restrict__ m1aw, const float* __restrict__ m1bw,
                                 const float* __restrict__ m2aw, const float* __restrict__ m2bw,
                                 bf16* __restrict__ Wt1, bf16* __restrict__ Wt2,
                                 bf16* __restrict__ Wt3, bf16* __restrict__ Wt4)
{
    const int R1 = HID * KPAD1;
    const int R2 = HID * HID;
    int idx = blockIdx.x * blockDim.x + threadIdx.x;
    if (idx < R1)                 wt_one(m1aw, Wt1, IN_DIM, KPAD1, idx);
    else if (idx < R1 + R2)       wt_one(m1bw, Wt2, HID, HID, idx - R1);
    else if (idx < R1 + 2 * R2)   wt_one(m2aw, Wt3, HID, HID, idx - R1 - R2);
    else if (idx < R1 + 3 * R2)   wt_one(m2bw, Wt4, HID, HID, idx - R1 - 2 * R2);
}

// ---------------------------------------------------------------------------
// feat f32 [N, IN_DIM] -> featbf bf16 [N, KPAD1] (cols >= IN_DIM zeroed).
__global__ void feat_to_bf16(const float* __restrict__ feat, bf16* __restrict__ featbf)
{
    int idx = blockIdx.x * blockDim.x + threadIdx.x;  // over N*KPAD1/4
    int r = idx / (KPAD1 / 4);
    int c4 = (idx - r * (KPAD1 / 4)) * 4;
    if (r >= N_NODES) return;
    bf16x4 o;
#pragma unroll
    for (int j = 0; j < 4; ++j) {
        int c = c4 + j;
        o[j] = (c < IN_DIM) ? (bf16)feat[(size_t)r * IN_DIM + c] : (bf16)0.0f;
    }
    *(bf16x4*)(featbf + (size_t)r * KPAD1 + c4) = o;
}

// ---------------------------------------------------------------------------
// colsum8[b&7][c] += partial column sums of feat; 1000 blocks x 192 thr.
__global__ void colsum_feat8(const float* __restrict__ feat, float* __restrict__ colsum8)
{
    int c  = threadIdx.x;
    int r0 = blockIdx.x * 50;
    if (c >= IN_DIM) return;
    float acc = 0.0f;
#pragma unroll 2
    for (int i = 0; i < 50; ++i) {
        int r = r0 + i;
        if (r < N_NODES) acc += feat[(size_t)r * IN_DIM + c];
    }
    atomicAdd(&colsum8[(blockIdx.x & 7) * KPAD1 + c], acc);
}

// ---------------------------------------------------------------------------
// CSR build.
__global__ void degree_hist(const int* __restrict__ dst, int* __restrict__ deg)
{
    int e = blockIdx.x * blockDim.x + threadIdx.x;
    atomicAdd(&deg[dst[e]], 1);
}

__global__ void block_degsum(const int* __restrict__ deg, int* __restrict__ bsum)
{
    __shared__ int s[256];
    int t = threadIdx.x;
    int idx = blockIdx.x * 256 + t;
    int v = (idx < N_NODES) ? deg[idx] : 0;
    s[t] = v;
    __syncthreads();
    for (int off = 128; off > 0; off >>= 1) {
        if (t < off) s[t] += s[t + off];
        __syncthreads();
    }
    if (t == 0) bsum[blockIdx.x] = s[0];
}

__global__ void scan_bsum(const int* __restrict__ bsum, int* __restrict__ gsum)
{
    __shared__ int s[256];
    int t = threadIdx.x;
    int v = (t < NB) ? bsum[t] : 0;
    s[t] = v;
    __syncthreads();
    for (int off = 1; off < 256; off <<= 1) {
        int u = (t >= off) ? s[t - off] : 0;
        __syncthreads();
        s[t] += u;
        __syncthreads();
    }
    gsum[t] = s[t] - v;
}

__global__ void block_scan_write(const int* __restrict__ deg, const int* __restrict__ gsum,
                                 int* __restrict__ rowptr, int* __restrict__ cursor)
{
    __shared__ int s[256];
    int t = threadIdx.x;
    int idx = blockIdx.x * 256 + t;
    int v = (idx < N_NODES) ? deg[idx] : 0;
    s[t] = v;
    __syncthreads();
    for (int off = 1; off < 256; off <<= 1) {
        int u = (t >= off) ? s[t - off] : 0;
        __syncthreads();
        s[t] += u;
        __syncthreads();
    }
    int excl = s[t] - v + gsum[blockIdx.x];
    if (idx < N_NODES) {
        rowptr[idx] = excl;
        cursor[idx] = excl;
    }
    if (idx == 0) rowptr[N_NODES] = N_EDGES;
}

__global__ void csr_fill(const int* __restrict__ src, const int* __restrict__ dst,
                         int* __restrict__ cursor, int* __restrict__ csr_src)
{
    int e = blockIdx.x * blockDim.x + threadIdx.x;
    int p = atomicAdd(&cursor[dst[e]], 1);
    csr_src[p] = src[e];
}

// ---------------------------------------------------------------------------
// Gather layer 1: xsum[n][:] = bf16( featbf[n][:] + sum featbf[src][:] )
__global__ void gather1(const bf16* __restrict__ featbf,
                        const int* __restrict__ rowptr,
                        const int* __restrict__ csr_src,
                        bf16* __restrict__ xsum)
{
    int wave = threadIdx.x >> 6;
    int lane = threadIdx.x & 63;
    int n = blockIdx.x * 4 + wave;
    if (n >= N_NODES) return;
    const int h   = lane >> 5;
    const int cl  = lane & 31;
    const int c   = cl * 8;
    const bool act = (cl < 24);        // 24*8 = 192

    f32x8 acc;
#pragma unroll
    for (int j = 0; j < 8; ++j) acc[j] = 0.0f;
    if (act && h == 0) {
        bf16x8 t0 = *(const bf16x8*)(featbf + (size_t)n * KPAD1 + c);
#pragma unroll
        for (int j = 0; j < 8; ++j) acc[j] = (float)t0[j];
    }

    int je = rowptr[n + 1];
    int jj = rowptr[n] + h;
    for (; jj + 6 < je; jj += 8) {
        int s0 = csr_src[jj], s1 = csr_src[jj + 2];
        int s2 = csr_src[jj + 4], s3 = csr_src[jj + 6];
        if (act) {
            bf16x8 u0 = *(const bf16x8*)(featbf + (size_t)s0 * KPAD1 + c);
            bf16x8 u1 = *(const bf16x8*)(featbf + (size_t)s1 * KPAD1 + c);
            bf16x8 u2 = *(const bf16x8*)(featbf + (size_t)s2 * KPAD1 + c);
            bf16x8 u3 = *(const bf16x8*)(featbf + (size_t)s3 * KPAD1 + c);
#pragma unroll
            for (int j = 0; j < 8; ++j)
                acc[j] += ((float)u0[j] + (float)u1[j]) + ((float)u2[j] + (float)u3[j]);
        }
    }
    for (; jj < je; jj += 2) {
        int s0 = csr_src[jj];
        if (act) {
            bf16x8 u0 = *(const bf16x8*)(featbf + (size_t)s0 * KPAD1 + c);
#pragma unroll
            for (int j = 0; j < 8; ++j) acc[j] += (float)u0[j];
        }
    }

#pragma unroll
    for (int j = 0; j < 8; ++j) acc[j] += __shfl_xor(acc[j], 32, 64);

    if (act && h == 0) {
        bf16x8 o;
#pragma unroll
        for (int j = 0; j < 8; ++j) o[j] = (bf16)acc[j];
        *(bf16x8*)(xsum + (size_t)n * KPAD1 + c) = o;
    }
}

// ---------------------------------------------------------------------------
// Gather layer 2: y2[n][:] = bf16( node1[n][:] + sum node1[src][:] )
__global__ void gather2(const bf16* __restrict__ node1,
                        const int* __restrict__ rowptr,
                        const int* __restrict__ csr_src,
                        bf16* __restrict__ y2)
{
    int wave = threadIdx.x >> 6;
    int lane = threadIdx.x & 63;
    int n = blockIdx.x * 4 + wave;
    if (n >= N_NODES) return;
    const int h  = lane >> 5;
    const int c  = (lane & 31) * 8;

    f32x8 acc;
    if (h == 0) {
        bf16x8 t0 = *(const bf16x8*)(node1 + (size_t)n * HID + c);
#pragma unroll
        for (int j = 0; j < 8; ++j) acc[j] = (float)t0[j];
    } else {
#pragma unroll
        for (int j = 0; j < 8; ++j) acc[j] = 0.0f;
    }

    int je = rowptr[n + 1];
    int jj = rowptr[n] + h;
    for (; jj + 6 < je; jj += 8) {
        int s0 = csr_src[jj], s1 = csr_src[jj + 2];
        int s2 = csr_src[jj + 4], s3 = csr_src[jj + 6];
        bf16x8 u0 = *(const bf16x8*)(node1 + (size_t)s0 * HID + c);
        bf16x8 u1 = *(const bf16x8*)(node1 + (size_t)s1 * HID + c);
        bf16x8 u2 = *(const bf16x8*)(node1 + (size_t)s2 * HID + c);
        bf16x8 u3 = *(const bf16x8*)(node1 + (size_t)s3 * HID + c);
#pragma unroll
        for (int j = 0; j < 8; ++j)
            acc[j] += ((float)u0[j] + (float)u1[j]) + ((float)u2[j] + (float)u3[j]);
    }
    for (; jj < je; jj += 2) {
        bf16x8 u0 = *(const bf16x8*)(node1 + (size_t)csr_src[jj] * HID + c);
#pragma unroll
        for (int j = 0; j < 8; ++j) acc[j] += (float)u0[j];
    }

#pragma unroll
    for (int j = 0; j < 8; ++j) acc[j] += __shfl_xor(acc[j], 32, 64);

    if (h == 0) {
        bf16x8 o;
#pragma unroll
        for (int j = 0; j < 8; ++j) o[j] = (bf16)acc[j];
        *(bf16x8*)(y2 + (size_t)n * HID + c) = o;
    }
}

// ---------------------------------------------------------------------------
// GEMM v3: wave = ALL 128 rows x 64 cols (was 32 rows x 256 cols).
// Per k-step a wave reads only its 2 j-tile B-frags (4 KB LDS vs 16 KB) ->
// block LDS-read = staged bytes (16 KB); removes the 4x LDS-read overshoot.
// A-frags (4 m-tiles) from global, L1-cached (16 KB/k-step shared by waves).
// A/B frag: row/col = lane&31, k = (lane>>5)*8 + j
// C/D     : col = lane&31, row = (reg&3) + 8*(reg>>2) + 4*(lane>>5)
template<int KPAD>
__launch_bounds__(256, 2)
__global__ void gemm_relu3(const bf16* __restrict__ X,
                           const bf16* __restrict__ Wt,
                           const float* __restrict__ bias,
                           bf16* __restrict__ out_bf,
                           float* __restrict__ colsum,   // nullable
                           int M)
{
    __shared__ __align__(128) bf16 sB[8192];   // 16 KB = 16 frag-blocks x 1 KB
    __shared__ float cs[256];

    const int tid  = threadIdx.x;
    const int w    = tid >> 6;
    const int lane = tid & 63;
    const int p    = lane >> 5;
    const int cn   = lane & 31;
    const int m0   = blockIdx.x * 128;

    int ar[4];
#pragma unroll
    for (int mt = 0; mt < 4; ++mt) {
        int r = m0 + mt * 32 + cn;
        ar[mt] = (r < M) ? r : (M - 1);   // clamp (stores guarded)
    }

    f32x16 acc[8];   // [mt*2 + jj]
#pragma unroll
    for (int e = 0; e < 8; ++e)
#pragma unroll
        for (int r = 0; r < 16; ++r) acc[e][r] = 0.0f;

    for (int k0 = 0; k0 < KPAD; k0 += 32) {
        __syncthreads();
#pragma unroll
        for (int i = 0; i < 4; ++i) {
            int fb = w * 4 + i;          // 0..15: j = fb>>1, kk = fb&1
            int j  = fb >> 1;
            int kk = fb & 1;
            const bf16* g = Wt + (size_t)(j * 32 + cn) * KPAD + k0 + kk * 16 + p * 8;
            GLDS16(g, sB + fb * 512);
        }
        __syncthreads();

#pragma unroll
        for (int kk = 0; kk < 2; ++kk) {
            bf16x8 a[4];
#pragma unroll
            for (int mt = 0; mt < 4; ++mt)
                a[mt] = *(const bf16x8*)(X + (size_t)ar[mt] * KPAD + k0 + kk * 16 + p * 8);
            bf16x8 b[2];
#pragma unroll
            for (int jj = 0; jj < 2; ++jj)
                b[jj] = *(const bf16x8*)(sB + ((w * 2 + jj) * 2 + kk) * 512 + lane * 8);
#pragma unroll
            for (int mt = 0; mt < 4; ++mt)
#pragma unroll
                for (int jj = 0; jj < 2; ++jj)
                    acc[mt * 2 + jj] = __builtin_amdgcn_mfma_f32_32x32x16_bf16(
                        a[mt], b[jj], acc[mt * 2 + jj], 0, 0, 0);
        }
    }

    if (colsum) {
        cs[tid] = 0.0f;
        __syncthreads();
    }

#pragma unroll
    for (int jj = 0; jj < 2; ++jj) {
        const int col = (w * 2 + jj) * 32 + cn;
        const float bv = bias[col];
        float part = 0.0f;
#pragma unroll
        for (int mt = 0; mt < 4; ++mt) {
#pragma unroll
            for (int r = 0; r < 16; ++r) {
                int row = m0 + mt * 32 + (r & 3) + 8 * (r >> 2) + 4 * p;
                if (row < M) {
                    float v = acc[mt * 2 + jj][r] + bv;
                    v = v > 0.0f ? v : 0.0f;
                    out_bf[(size_t)row * HID + col] = (bf16)v;
                    part += v;
                }
            }
        }
        if (colsum) {
            part += __shfl_xor(part, 32, 64);   // combine the two p-halves
            if (p == 0) atomicAdd(&cs[col], part);
        }
    }

    if (colsum) {
        __syncthreads();
        atomicAdd(&colsum[tid], cs[tid]);
    }
}

// ---------------------------------------------------------------------------
// Graph head: three GEMVs + sum + final GEMV, single block of 256 threads.
__global__ void graph_head(const float* __restrict__ cs0_8,
                           const float* __restrict__ cs1,
                           const float* __restrict__ cs2,
                           const float* __restrict__ g0w, const float* __restrict__ g0b,
                           const float* __restrict__ g1w, const float* __restrict__ g1b,
                           const float* __restrict__ g2w, const float* __restrict__ g2b,
                           const float* __restrict__ glw, const float* __restrict__ glb,
                           float* __restrict__ gvec)
{
    __shared__ float v0[IN_DIM], v1[HID], v2[HID], gs[HID];
    int t = threadIdx.x;
    if (t < IN_DIM) {
        float s = 0.0f;
#pragma unroll
        for (int i = 0; i < 8; ++i) s += cs0_8[i * KPAD1 + t];
        v0[t] = s;
    }
    v1[t] = cs1[t];
    v2[t] = cs2[t];
    __syncthreads();

    float a0 = 0.0f, a1 = 0.0f, a2 = 0.0f;
    for (int k = 0; k < IN_DIM; ++k) a0 += v0[k] * g0w[k * HID + t];
    for (int k = 0; k < HID; ++k) {
        a1 += v1[k] * g1w[k * HID + t];
        a2 += v2[k] * g2w[k * HID + t];
    }
    float e0 = fmaxf(a0 + g0b[t], 0.0f);
    float e1 = fmaxf(a1 + g1b[t], 0.0f);
    float e2 = fmaxf(a2 + g2b[t], 0.0f);
    gs[t] = e0 + e1 + e2;
    __syncthreads();

    float a3 = 0.0f;
    for (int k = 0; k < HID; ++k) a3 += gs[k] * glw[k * HID + t];
    gvec[t] = fmaxf(a3 + glb[t], 0.0f);
}

// ---------------------------------------------------------------------------
// out[n,c] = node2[n,c](bf16) + gvec[c] (f32 out); 4 elements per thread.
__global__ void final_add(const bf16* __restrict__ node2,
                          const float* __restrict__ gvec,
                          float* __restrict__ out)
{
    int idx = blockIdx.x * blockDim.x + threadIdx.x;
    size_t base = (size_t)idx * 4;
    int c = (int)(base & (HID - 1));
    bf16x4 v = *(const bf16x4*)(node2 + base);
    f32x4 g = *(const f32x4*)(gvec + c);
    f32x4 o;
#pragma unroll
    for (int j = 0; j < 4; ++j) o[j] = (float)v[j] + g[j];
    *(f32x4*)(out + base) = o;
}

// ---------------------------------------------------------------------------
extern "C" void kernel_launch(void* const* d_in, const int* in_sizes, int n_in,
                              void* d_out, int out_size, void* d_ws, size_t ws_size,
                              hipStream_t stream)
{
    const float* feat = (const float*)d_in[0];
    const int*   ei   = (const int*)d_in[1];
    const int*   src  = ei;
    const int*   dst  = ei + N_EDGES;
    const float* g0w = (const float*)d_in[2],  *g0b = (const float*)d_in[3];
    const float* g1w = (const float*)d_in[4],  *g1b = (const float*)d_in[5];
    const float* g2w = (const float*)d_in[6],  *g2b = (const float*)d_in[7];
    const float* glw = (const float*)d_in[8],  *glb = (const float*)d_in[9];
    const float* m1aw = (const float*)d_in[10], *m1ab = (const float*)d_in[11];
    const float* m1bw = (const float*)d_in[12], *m1bb = (const float*)d_in[13];
    const float* m2aw = (const float*)d_in[14], *m2ab = (const float*)d_in[15];
    const float* m2bw = (const float*)d_in[16], *m2bb = (const float*)d_in[17];
    float* out = (float*)d_out;

    char* ws = (char*)d_ws;
    size_t off = 0;
    auto alloc = [&](size_t bytes) -> void* {
        void* p = ws + off;
        off += (bytes + 255) & ~(size_t)255;
        return p;
    };
    bf16*  featbf = (bf16*)alloc((size_t)N_NODES * KPAD1 * 2);
    bf16*  xsum  = (bf16*) alloc((size_t)N_NODES * KPAD1 * 2);
    bf16*  y2    = (bf16*) alloc((size_t)N_NODES * HID * 2);
    bf16*  node2 = (bf16*) alloc((size_t)N_NODES * HID * 2);
    bf16*  h1    = (bf16*) alloc((size_t)N_NODES * HID * 2);   // reused as h2
    bf16*  node1 = (bf16*) alloc((size_t)N_NODES * HID * 2);
    bf16*  Wt1   = (bf16*) alloc((size_t)HID * KPAD1 * 2);
    bf16*  Wt2   = (bf16*) alloc((size_t)HID * HID * 2);
    bf16*  Wt3   = (bf16*) alloc((size_t)HID * HID * 2);
    bf16*  Wt4   = (bf16*) alloc((size_t)HID * HID * 2);
    int*   deg     = (int*)alloc((size_t)N_NODES * 4);
    int*   rowptr  = (int*)alloc((size_t)(N_NODES + 1) * 4);
    int*   cursor  = (int*)alloc((size_t)N_NODES * 4);
    int*   csr_src = (int*)alloc((size_t)N_EDGES * 4);
    int*   bsum    = (int*)alloc(256 * 4);
    int*   gsum    = (int*)alloc(256 * 4);
    float* csums   = (float*)alloc((8 * KPAD1 + 256 + 256 + 256) * 4);
    float* colsum0_8 = csums;                    // 8 x 192 partial slots
    float* colsum1   = csums + 8 * KPAD1;        // 256
    float* colsum2   = csums + 8 * KPAD1 + 256;  // 256
    float* gvec      = csums + 8 * KPAD1 + 512;  // 256

    hipMemsetAsync(csums, 0, (8 * KPAD1 + 512) * 4, stream);
    hipMemsetAsync(deg, 0, (size_t)N_NODES * 4, stream);

    // all 4 weight transposes, one launch
    wt_transpose_all<<<(HID * KPAD1 + 3 * HID * HID + 255) / 256, 256, 0, stream>>>(
        m1aw, m1bw, m2aw, m2bw, Wt1, Wt2, Wt3, Wt4);

    // feat -> bf16 (wide vectorized grid)
    feat_to_bf16<<<((size_t)N_NODES * (KPAD1 / 4) + 255) / 256, 256, 0, stream>>>(feat, featbf);
    // colsum0 partials (8-slot spread)
    colsum_feat8<<<1000, 192, 0, stream>>>(feat, colsum0_8);

    // CSR build (grouped by dst)
    degree_hist<<<N_EDGES / 256, 256, 0, stream>>>(dst, deg);
    block_degsum<<<NB, 256, 0, stream>>>(deg, bsum);
    scan_bsum<<<1, 256, 0, stream>>>(bsum, gsum);
    block_scan_write<<<NB, 256, 0, stream>>>(deg, gsum, rowptr, cursor);
    csr_fill<<<N_EDGES / 256, 256, 0, stream>>>(src, dst, cursor, csr_src);

    // xsum = bf16(feat + gather(feat))
    gather1<<<(N_NODES + 3) / 4, 256, 0, stream>>>(featbf, rowptr, csr_src, xsum);

    const int gblocks = (N_NODES + 127) / 128;
    // h1 = relu(xsum @ m1a_w + b)
    gemm_relu3<KPAD1><<<gblocks, 256, 0, stream>>>(xsum, Wt1, m1ab, h1, nullptr, N_NODES);
    // node1 = relu(h1 @ m1b_w + b), colsum1 fused
    gemm_relu3<HID><<<gblocks, 256, 0, stream>>>(h1, Wt2, m1bb, node1, colsum1, N_NODES);
    // y2 = bf16(node1 + gather(node1))
    gather2<<<(N_NODES + 3) / 4, 256, 0, stream>>>(node1, rowptr, csr_src, y2);
    // h2 = relu(y2 @ m2a_w + b)  (reuse h1 buffer)
    gemm_relu3<HID><<<gblocks, 256, 0, stream>>>(y2, Wt3, m2ab, h1, nullptr, N_NODES);
    // node2 = relu(h2 @ m2b_w + b), colsum2 fused
    gemm_relu3<HID><<<gblocks, 256, 0, stream>>>(h1, Wt4, m2bb, node2, colsum2, N_NODES);
    // graph head -> gvec = g_last
    graph_head<<<1, 256, 0, stream>>>(colsum0_8, colsum1, colsum2,
                                      g0w, g0b, g1w, g1b, g2w, g2b, glw, glb, gvec);
    // out = node2 + gvec
    final_add<<<((size_t)N_NODES * HID / 4 + 255) / 256, 256, 0, stream>>>(node2, gvec, out);
    (void)in_sizes; (void)n_in; (void)out_size; (void)ws_size;
}

// Round 9
// 548.348 us; speedup vs baseline: 1.0176x; 1.0176x over previous
//
#include <hip/hip_runtime.h>

#define N_NODES 50000
#define N_EDGES 800000
#define IN_DIM  162
#define HID     256
#define KPAD1   192   // IN_DIM padded to multiple of 32
#define NB      ((N_NODES + 255) / 256)   // 196 scan blocks

typedef __bf16 bf16;
typedef __bf16 bf16x8 __attribute__((ext_vector_type(8)));
typedef __bf16 bf16x4 __attribute__((ext_vector_type(4)));
typedef float  f32x4  __attribute__((ext_vector_type(4)));
typedef float  f32x8  __attribute__((ext_vector_type(8)));
typedef float  f32x16 __attribute__((ext_vector_type(16)));

#define GLDS16(g, l) __builtin_amdgcn_global_load_lds( \
    (const __attribute__((address_space(1))) void*)(g), \
    (__attribute__((address_space(3))) void*)(l), 16, 0, 0)

// ---------------------------------------------------------------------------
// Fused prep: feat f32 -> featbf bf16 padded  PLUS  all 4 weight transposes.
#define FEAT_UNITS (N_NODES * (KPAD1 / 4))     // 2,400,000 bf16x4 units
#define R1 (HID * KPAD1)
#define R2 (HID * HID)

__device__ __forceinline__ void wt_one(const float* W, bf16* Wt, int K, int KPAD, int idx)
{
    int n = idx / KPAD;
    int k = idx - n * KPAD;
    Wt[idx] = (k < K) ? (bf16)W[(size_t)k * HID + n] : (bf16)0.0f;
}

__global__ void prep_kernel(const float* __restrict__ feat, bf16* __restrict__ featbf,
                            const float* __restrict__ m1aw, const float* __restrict__ m1bw,
                            const float* __restrict__ m2aw, const float* __restrict__ m2bw,
                            bf16* __restrict__ Wt1, bf16* __restrict__ Wt2,
                            bf16* __restrict__ Wt3, bf16* __restrict__ Wt4)
{
    int idx = blockIdx.x * blockDim.x + threadIdx.x;
    if (idx < FEAT_UNITS) {
        int r = idx / (KPAD1 / 4);
        int c4 = (idx - r * (KPAD1 / 4)) * 4;
        bf16x4 o;
#pragma unroll
        for (int j = 0; j < 4; ++j) {
            int c = c4 + j;
            o[j] = (c < IN_DIM) ? (bf16)feat[(size_t)r * IN_DIM + c] : (bf16)0.0f;
        }
        *(bf16x4*)(featbf + (size_t)r * KPAD1 + c4) = o;
        return;
    }
    int w = idx - FEAT_UNITS;
    if (w < R1)                 wt_one(m1aw, Wt1, IN_DIM, KPAD1, w);
    else if (w < R1 + R2)       wt_one(m1bw, Wt2, HID, HID, w - R1);
    else if (w < R1 + 2 * R2)   wt_one(m2aw, Wt3, HID, HID, w - R1 - R2);
    else if (w < R1 + 3 * R2)   wt_one(m2bw, Wt4, HID, HID, w - R1 - 2 * R2);
}

// ---------------------------------------------------------------------------
// colsum8[b&7][c] += partial column sums of feat; 1000 blocks x 192 thr.
__global__ void colsum_feat8(const float* __restrict__ feat, float* __restrict__ colsum8)
{
    int c  = threadIdx.x;
    int r0 = blockIdx.x * 50;
    if (c >= IN_DIM) return;
    float acc = 0.0f;
#pragma unroll 2
    for (int i = 0; i < 50; ++i) {
        int r = r0 + i;
        if (r < N_NODES) acc += feat[(size_t)r * IN_DIM + c];
    }
    atomicAdd(&colsum8[(blockIdx.x & 7) * KPAD1 + c], acc);
}

// ---------------------------------------------------------------------------
// CSR build.
__global__ void degree_hist(const int* __restrict__ dst, int* __restrict__ deg)
{
    int e = blockIdx.x * blockDim.x + threadIdx.x;
    atomicAdd(&deg[dst[e]], 1);
}

__global__ void block_degsum(const int* __restrict__ deg, int* __restrict__ bsum)
{
    __shared__ int s[256];
    int t = threadIdx.x;
    int idx = blockIdx.x * 256 + t;
    int v = (idx < N_NODES) ? deg[idx] : 0;
    s[t] = v;
    __syncthreads();
    for (int off = 128; off > 0; off >>= 1) {
        if (t < off) s[t] += s[t + off];
        __syncthreads();
    }
    if (t == 0) bsum[blockIdx.x] = s[0];
}

__global__ void scan_bsum(const int* __restrict__ bsum, int* __restrict__ gsum)
{
    __shared__ int s[256];
    int t = threadIdx.x;
    int v = (t < NB) ? bsum[t] : 0;
    s[t] = v;
    __syncthreads();
    for (int off = 1; off < 256; off <<= 1) {
        int u = (t >= off) ? s[t - off] : 0;
        __syncthreads();
        s[t] += u;
        __syncthreads();
    }
    gsum[t] = s[t] - v;
}

__global__ void block_scan_write(const int* __restrict__ deg, const int* __restrict__ gsum,
                                 int* __restrict__ rowptr, int* __restrict__ cursor)
{
    __shared__ int s[256];
    int t = threadIdx.x;
    int idx = blockIdx.x * 256 + t;
    int v = (idx < N_NODES) ? deg[idx] : 0;
    s[t] = v;
    __syncthreads();
    for (int off = 1; off < 256; off <<= 1) {
        int u = (t >= off) ? s[t - off] : 0;
        __syncthreads();
        s[t] += u;
        __syncthreads();
    }
    int excl = s[t] - v + gsum[blockIdx.x];
    if (idx < N_NODES) {
        rowptr[idx] = excl;
        cursor[idx] = excl;
    }
    if (idx == 0) rowptr[N_NODES] = N_EDGES;
}

__global__ void csr_fill(const int* __restrict__ src, const int* __restrict__ dst,
                         int* __restrict__ cursor, int* __restrict__ csr_src)
{
    int e = blockIdx.x * blockDim.x + threadIdx.x;
    int p = atomicAdd(&cursor[dst[e]], 1);
    csr_src[p] = src[e];
}

// ---------------------------------------------------------------------------
// Gather layer 1: xsum[n][:] = bf16( featbf[n][:] + sum featbf[src][:] )
// Half-wave per src-parity, 16B/lane (24 active lanes = 384B row); main loop
// 8 rows per half (16/iter), mid 4 (8/iter), pair tail. shfl_xor(32) reduce.
__global__ void gather1(const bf16* __restrict__ featbf,
                        const int* __restrict__ rowptr,
                        const int* __restrict__ csr_src,
                        bf16* __restrict__ xsum)
{
    int wave = threadIdx.x >> 6;
    int lane = threadIdx.x & 63;
    int n = blockIdx.x * 4 + wave;
    if (n >= N_NODES) return;
    const int h   = lane >> 5;
    const int cl  = lane & 31;
    const int c   = cl * 8;
    const bool act = (cl < 24);        // 24*8 = 192

    f32x8 acc;
#pragma unroll
    for (int j = 0; j < 8; ++j) acc[j] = 0.0f;
    if (act && h == 0) {
        bf16x8 t0 = *(const bf16x8*)(featbf + (size_t)n * KPAD1 + c);
#pragma unroll
        for (int j = 0; j < 8; ++j) acc[j] = (float)t0[j];
    }

    int je = rowptr[n + 1];
    int jj = rowptr[n] + h;
    for (; jj + 14 < je; jj += 16) {
        int s[8];
#pragma unroll
        for (int i = 0; i < 8; ++i) s[i] = csr_src[jj + 2 * i];
        if (act) {
            bf16x8 u[8];
#pragma unroll
            for (int i = 0; i < 8; ++i)
                u[i] = *(const bf16x8*)(featbf + (size_t)s[i] * KPAD1 + c);
#pragma unroll
            for (int j = 0; j < 8; ++j)
                acc[j] += (((float)u[0][j] + (float)u[1][j]) + ((float)u[2][j] + (float)u[3][j]))
                        + (((float)u[4][j] + (float)u[5][j]) + ((float)u[6][j] + (float)u[7][j]));
        }
    }
    for (; jj + 6 < je; jj += 8) {
        int s0 = csr_src[jj], s1 = csr_src[jj + 2];
        int s2 = csr_src[jj + 4], s3 = csr_src[jj + 6];
        if (act) {
            bf16x8 u0 = *(const bf16x8*)(featbf + (size_t)s0 * KPAD1 + c);
            bf16x8 u1 = *(const bf16x8*)(featbf + (size_t)s1 * KPAD1 + c);
            bf16x8 u2 = *(const bf16x8*)(featbf + (size_t)s2 * KPAD1 + c);
            bf16x8 u3 = *(const bf16x8*)(featbf + (size_t)s3 * KPAD1 + c);
#pragma unroll
            for (int j = 0; j < 8; ++j)
                acc[j] += ((float)u0[j] + (float)u1[j]) + ((float)u2[j] + (float)u3[j]);
        }
    }
    for (; jj < je; jj += 2) {
        int s0 = csr_src[jj];
        if (act) {
            bf16x8 u0 = *(const bf16x8*)(featbf + (size_t)s0 * KPAD1 + c);
#pragma unroll
            for (int j = 0; j < 8; ++j) acc[j] += (float)u0[j];
        }
    }

#pragma unroll
    for (int j = 0; j < 8; ++j) acc[j] += __shfl_xor(acc[j], 32, 64);

    if (act && h == 0) {
        bf16x8 o;
#pragma unroll
        for (int j = 0; j < 8; ++j) o[j] = (bf16)acc[j];
        *(bf16x8*)(xsum + (size_t)n * KPAD1 + c) = o;
    }
}

// ---------------------------------------------------------------------------
// Gather layer 2: y2[n][:] = bf16( node1[n][:] + sum node1[src][:] )
// Half-wave per src-parity, 16B/lane (32 lanes = 512B row); main loop 8 rows
// per half (16/iter), mid 4 (8/iter), pair tail. shfl_xor(32) reduce.
__global__ void gather2(const bf16* __restrict__ node1,
                        const int* __restrict__ rowptr,
                        const int* __restrict__ csr_src,
                        bf16* __restrict__ y2)
{
    int wave = threadIdx.x >> 6;
    int lane = threadIdx.x & 63;
    int n = blockIdx.x * 4 + wave;
    if (n >= N_NODES) return;
    const int h  = lane >> 5;
    const int c  = (lane & 31) * 8;

    f32x8 acc;
    if (h == 0) {
        bf16x8 t0 = *(const bf16x8*)(node1 + (size_t)n * HID + c);
#pragma unroll
        for (int j = 0; j < 8; ++j) acc[j] = (float)t0[j];
    } else {
#pragma unroll
        for (int j = 0; j < 8; ++j) acc[j] = 0.0f;
    }

    int je = rowptr[n + 1];
    int jj = rowptr[n] + h;
    for (; jj + 14 < je; jj += 16) {
        int s[8];
#pragma unroll
        for (int i = 0; i < 8; ++i) s[i] = csr_src[jj + 2 * i];
        bf16x8 u[8];
#pragma unroll
        for (int i = 0; i < 8; ++i)
            u[i] = *(const bf16x8*)(node1 + (size_t)s[i] * HID + c);
#pragma unroll
        for (int j = 0; j < 8; ++j)
            acc[j] += (((float)u[0][j] + (float)u[1][j]) + ((float)u[2][j] + (float)u[3][j]))
                    + (((float)u[4][j] + (float)u[5][j]) + ((float)u[6][j] + (float)u[7][j]));
    }
    for (; jj + 6 < je; jj += 8) {
        int s0 = csr_src[jj], s1 = csr_src[jj + 2];
        int s2 = csr_src[jj + 4], s3 = csr_src[jj + 6];
        bf16x8 u0 = *(const bf16x8*)(node1 + (size_t)s0 * HID + c);
        bf16x8 u1 = *(const bf16x8*)(node1 + (size_t)s1 * HID + c);
        bf16x8 u2 = *(const bf16x8*)(node1 + (size_t)s2 * HID + c);
        bf16x8 u3 = *(const bf16x8*)(node1 + (size_t)s3 * HID + c);
#pragma unroll
        for (int j = 0; j < 8; ++j)
            acc[j] += ((float)u0[j] + (float)u1[j]) + ((float)u2[j] + (float)u3[j]);
    }
    for (; jj < je; jj += 2) {
        bf16x8 u0 = *(const bf16x8*)(node1 + (size_t)csr_src[jj] * HID + c);
#pragma unroll
        for (int j = 0; j < 8; ++j) acc[j] += (float)u0[j];
    }

#pragma unroll
    for (int j = 0; j < 8; ++j) acc[j] += __shfl_xor(acc[j], 32, 64);

    if (h == 0) {
        bf16x8 o;
#pragma unroll
        for (int j = 0; j < 8; ++j) o[j] = (bf16)acc[j];
        *(bf16x8*)(y2 + (size_t)n * HID + c) = o;
    }
}

// ---------------------------------------------------------------------------
// GEMM v2 (reverted from v3 — v3's 128-row A-reads per wave regressed 23 µs).
// Block = 4 waves, tile 128 rows x 256 cols; wave w owns rows [w*32,w*32+32)
// x 256 cols = 8 x mfma_f32_32x32x16_bf16. Wt k-slice staged frag-major in
// LDS via global_load_lds width=16 (conflict-free ds_read_b128).
// A/B frag: row/col = lane&31, k = (lane>>5)*8 + j
// C/D     : col = lane&31, row = (reg&3) + 8*(reg>>2) + 4*(lane>>5)
template<int KPAD>
__launch_bounds__(256)
__global__ void gemm_relu2(const bf16* __restrict__ X,
                           const bf16* __restrict__ Wt,
                           const float* __restrict__ bias,
                           bf16* __restrict__ out_bf,
                           float* __restrict__ colsum,   // nullable
                           int M)
{
    __shared__ __align__(128) bf16 sB[8192];   // 16 KB
    __shared__ float cs[256];

    const int tid  = threadIdx.x;
    const int w    = tid >> 6;
    const int lane = tid & 63;
    const int p    = lane >> 5;
    const int cn   = lane & 31;
    const int m_base = blockIdx.x * 128 + w * 32;

    int arow = m_base + cn;
    if (arow >= M) arow = M - 1;   // clamp (stores guarded)

    f32x16 acc[8];
#pragma unroll
    for (int j = 0; j < 8; ++j)
#pragma unroll
        for (int r = 0; r < 16; ++r) acc[j][r] = 0.0f;

    for (int k0 = 0; k0 < KPAD; k0 += 32) {
        __syncthreads();
#pragma unroll
        for (int i = 0; i < 4; ++i) {
            int fb = w * 4 + i;
            int j  = fb >> 1;
            int kk = fb & 1;
            const bf16* g = Wt + (size_t)(j * 32 + cn) * KPAD + k0 + kk * 16 + p * 8;
            GLDS16(g, sB + fb * 512);
        }
        __syncthreads();

#pragma unroll
        for (int kk = 0; kk < 2; ++kk) {
            bf16x8 a = *(const bf16x8*)(X + (size_t)arow * KPAD + k0 + kk * 16 + p * 8);
#pragma unroll
            for (int j = 0; j < 8; ++j) {
                bf16x8 b = *(const bf16x8*)(sB + (j * 2 + kk) * 512 + lane * 8);
                acc[j] = __builtin_amdgcn_mfma_f32_32x32x16_bf16(a, b, acc[j], 0, 0, 0);
            }
        }
    }

    if (colsum) {
        cs[tid] = 0.0f;
        __syncthreads();
    }

#pragma unroll
    for (int j = 0; j < 8; ++j) {
        const int col = j * 32 + cn;
        const float bv = bias[col];
        float part = 0.0f;
#pragma unroll
        for (int r = 0; r < 16; ++r) {
            int rl = (r & 3) + 8 * (r >> 2) + 4 * p;
            int mo = m_base + rl;
            if (mo < M) {
                float v = acc[j][r] + bv;
                v = v > 0.0f ? v : 0.0f;
                out_bf[(size_t)mo * HID + col] = (bf16)v;
                part += v;
            }
        }
        if (colsum) {
            part += __shfl_xor(part, 32, 64);   // combine the two p-halves
            if (p == 0) atomicAdd(&cs[col], part);
        }
    }

    if (colsum) {
        __syncthreads();
        atomicAdd(&colsum[tid], cs[tid]);
    }
}

// ---------------------------------------------------------------------------
// Graph head: three GEMVs + sum + final GEMV, single block of 256 threads.
__global__ void graph_head(const float* __restrict__ cs0_8,
                           const float* __restrict__ cs1,
                           const float* __restrict__ cs2,
                           const float* __restrict__ g0w, const float* __restrict__ g0b,
                           const float* __restrict__ g1w, const float* __restrict__ g1b,
                           const float* __restrict__ g2w, const float* __restrict__ g2b,
                           const float* __restrict__ glw, const float* __restrict__ glb,
                           float* __restrict__ gvec)
{
    __shared__ float v0[IN_DIM], v1[HID], v2[HID], gs[HID];
    int t = threadIdx.x;
    if (t < IN_DIM) {
        float s = 0.0f;
#pragma unroll
        for (int i = 0; i < 8; ++i) s += cs0_8[i * KPAD1 + t];
        v0[t] = s;
    }
    v1[t] = cs1[t];
    v2[t] = cs2[t];
    __syncthreads();

    float a0 = 0.0f, a1 = 0.0f, a2 = 0.0f;
    for (int k = 0; k < IN_DIM; ++k) a0 += v0[k] * g0w[k * HID + t];
    for (int k = 0; k < HID; ++k) {
        a1 += v1[k] * g1w[k * HID + t];
        a2 += v2[k] * g2w[k * HID + t];
    }
    float e0 = fmaxf(a0 + g0b[t], 0.0f);
    float e1 = fmaxf(a1 + g1b[t], 0.0f);
    float e2 = fmaxf(a2 + g2b[t], 0.0f);
    gs[t] = e0 + e1 + e2;
    __syncthreads();

    float a3 = 0.0f;
    for (int k = 0; k < HID; ++k) a3 += gs[k] * glw[k * HID + t];
    gvec[t] = fmaxf(a3 + glb[t], 0.0f);
}

// ---------------------------------------------------------------------------
// out[n,c] = node2[n,c](bf16) + gvec[c] (f32 out); 4 elements per thread.
__global__ void final_add(const bf16* __restrict__ node2,
                          const float* __restrict__ gvec,
                          float* __restrict__ out)
{
    int idx = blockIdx.x * blockDim.x + threadIdx.x;
    size_t base = (size_t)idx * 4;
    int c = (int)(base & (HID - 1));
    bf16x4 v = *(const bf16x4*)(node2 + base);
    f32x4 g = *(const f32x4*)(gvec + c);
    f32x4 o;
#pragma unroll
    for (int j = 0; j < 4; ++j) o[j] = (float)v[j] + g[j];
    *(f32x4*)(out + base) = o;
}

// ---------------------------------------------------------------------------
extern "C" void kernel_launch(void* const* d_in, const int* in_sizes, int n_in,
                              void* d_out, int out_size, void* d_ws, size_t ws_size,
                              hipStream_t stream)
{
    const float* feat = (const float*)d_in[0];
    const int*   ei   = (const int*)d_in[1];
    const int*   src  = ei;
    const int*   dst  = ei + N_EDGES;
    const float* g0w = (const float*)d_in[2],  *g0b = (const float*)d_in[3];
    const float* g1w = (const float*)d_in[4],  *g1b = (const float*)d_in[5];
    const float* g2w = (const float*)d_in[6],  *g2b = (const float*)d_in[7];
    const float* glw = (const float*)d_in[8],  *glb = (const float*)d_in[9];
    const float* m1aw = (const float*)d_in[10], *m1ab = (const float*)d_in[11];
    const float* m1bw = (const float*)d_in[12], *m1bb = (const float*)d_in[13];
    const float* m2aw = (const float*)d_in[14], *m2ab = (const float*)d_in[15];
    const float* m2bw = (const float*)d_in[16], *m2bb = (const float*)d_in[17];
    float* out = (float*)d_out;

    char* ws = (char*)d_ws;
    size_t off = 0;
    auto alloc = [&](size_t bytes) -> void* {
        void* p = ws + off;
        off += (bytes + 255) & ~(size_t)255;
        return p;
    };
    bf16*  featbf = (bf16*)alloc((size_t)N_NODES * KPAD1 * 2);
    bf16*  xsum  = (bf16*) alloc((size_t)N_NODES * KPAD1 * 2);
    bf16*  y2    = (bf16*) alloc((size_t)N_NODES * HID * 2);
    bf16*  node2 = (bf16*) alloc((size_t)N_NODES * HID * 2);
    bf16*  h1    = (bf16*) alloc((size_t)N_NODES * HID * 2);   // reused as h2
    bf16*  node1 = (bf16*) alloc((size_t)N_NODES * HID * 2);
    bf16*  Wt1   = (bf16*) alloc((size_t)HID * KPAD1 * 2);
    bf16*  Wt2   = (bf16*) alloc((size_t)HID * HID * 2);
    bf16*  Wt3   = (bf16*) alloc((size_t)HID * HID * 2);
    bf16*  Wt4   = (bf16*) alloc((size_t)HID * HID * 2);
    int*   deg     = (int*)alloc((size_t)N_NODES * 4);
    int*   rowptr  = (int*)alloc((size_t)(N_NODES + 1) * 4);
    int*   cursor  = (int*)alloc((size_t)N_NODES * 4);
    int*   csr_src = (int*)alloc((size_t)N_EDGES * 4);
    int*   bsum    = (int*)alloc(256 * 4);
    int*   gsum    = (int*)alloc(256 * 4);
    float* csums   = (float*)alloc((8 * KPAD1 + 256 + 256 + 256) * 4);
    float* colsum0_8 = csums;                    // 8 x 192 partial slots
    float* colsum1   = csums + 8 * KPAD1;        // 256
    float* colsum2   = csums + 8 * KPAD1 + 256;  // 256
    float* gvec      = csums + 8 * KPAD1 + 512;  // 256

    hipMemsetAsync(csums, 0, (8 * KPAD1 + 512) * 4, stream);
    hipMemsetAsync(deg, 0, (size_t)N_NODES * 4, stream);

    // fused feat->bf16 + all weight transposes
    prep_kernel<<<(FEAT_UNITS + R1 + 3 * R2 + 255) / 256, 256, 0, stream>>>(
        feat, featbf, m1aw, m1bw, m2aw, m2bw, Wt1, Wt2, Wt3, Wt4);
    // colsum0 partials (8-slot spread)
    colsum_feat8<<<1000, 192, 0, stream>>>(feat, colsum0_8);

    // CSR build (grouped by dst)
    degree_hist<<<N_EDGES / 256, 256, 0, stream>>>(dst, deg);
    block_degsum<<<NB, 256, 0, stream>>>(deg, bsum);
    scan_bsum<<<1, 256, 0, stream>>>(bsum, gsum);
    block_scan_write<<<NB, 256, 0, stream>>>(deg, gsum, rowptr, cursor);
    csr_fill<<<N_EDGES / 256, 256, 0, stream>>>(src, dst, cursor, csr_src);

    // xsum = bf16(feat + gather(feat))
    gather1<<<(N_NODES + 3) / 4, 256, 0, stream>>>(featbf, rowptr, csr_src, xsum);

    const int gblocks = (N_NODES + 127) / 128;
    // h1 = relu(xsum @ m1a_w + b)
    gemm_relu2<KPAD1><<<gblocks, 256, 0, stream>>>(xsum, Wt1, m1ab, h1, nullptr, N_NODES);
    // node1 = relu(h1 @ m1b_w + b), colsum1 fused
    gemm_relu2<HID><<<gblocks, 256, 0, stream>>>(h1, Wt2, m1bb, node1, colsum1, N_NODES);
    // y2 = bf16(node1 + gather(node1))
    gather2<<<(N_NODES + 3) / 4, 256, 0, stream>>>(node1, rowptr, csr_src, y2);
    // h2 = relu(y2 @ m2a_w + b)  (reuse h1 buffer)
    gemm_relu2<HID><<<gblocks, 256, 0, stream>>>(y2, Wt3, m2ab, h1, nullptr, N_NODES);
    // node2 = relu(h2 @ m2b_w + b), colsum2 fused
    gemm_relu2<HID><<<gblocks, 256, 0, stream>>>(h1, Wt4, m2bb, node2, colsum2, N_NODES);
    // graph head -> gvec = g_last
    graph_head<<<1, 256, 0, stream>>>(colsum0_8, colsum1, colsum2,
                                      g0w, g0b, g1w, g1b, g2w, g2b, glw, glb, gvec);
    // out = node2 + gvec
    final_add<<<((size_t)N_NODES * HID / 4 + 255) / 256, 256, 0, stream>>>(node2, gvec, out);
    (void)in_sizes; (void)n_in; (void)out_size; (void)ws_size;
}

// Round 10
// 536.698 us; speedup vs baseline: 1.0397x; 1.0217x over previous
//
#include <hip/hip_runtime.h>

#define N_NODES 50000
#define N_EDGES 800000
#define IN_DIM  162
#define HID     256
#define KPAD1   192   // IN_DIM padded to multiple of 32
#define NB      ((N_NODES + 255) / 256)   // 196 scan blocks

typedef __bf16 bf16;
typedef __bf16 bf16x8 __attribute__((ext_vector_type(8)));
typedef __bf16 bf16x4 __attribute__((ext_vector_type(4)));
typedef float  f32x4  __attribute__((ext_vector_type(4)));
typedef float  f32x8  __attribute__((ext_vector_type(8)));
typedef float  f32x16 __attribute__((ext_vector_type(16)));

#define GLDS16(g, l) __builtin_amdgcn_global_load_lds( \
    (const __attribute__((address_space(1))) void*)(g), \
    (__attribute__((address_space(3))) void*)(l), 16, 0, 0)

// ---------------------------------------------------------------------------
// Fused prep: feat f32 -> featbf bf16 padded  PLUS  all 4 weight transposes.
#define FEAT_UNITS (N_NODES * (KPAD1 / 4))     // 2,400,000 bf16x4 units
#define R1 (HID * KPAD1)
#define R2 (HID * HID)

__device__ __forceinline__ void wt_one(const float* W, bf16* Wt, int K, int KPAD, int idx)
{
    int n = idx / KPAD;
    int k = idx - n * KPAD;
    Wt[idx] = (k < K) ? (bf16)W[(size_t)k * HID + n] : (bf16)0.0f;
}

__global__ void prep_kernel(const float* __restrict__ feat, bf16* __restrict__ featbf,
                            const float* __restrict__ m1aw, const float* __restrict__ m1bw,
                            const float* __restrict__ m2aw, const float* __restrict__ m2bw,
                            bf16* __restrict__ Wt1, bf16* __restrict__ Wt2,
                            bf16* __restrict__ Wt3, bf16* __restrict__ Wt4)
{
    int idx = blockIdx.x * blockDim.x + threadIdx.x;
    if (idx < FEAT_UNITS) {
        int r = idx / (KPAD1 / 4);
        int c4 = (idx - r * (KPAD1 / 4)) * 4;
        bf16x4 o;
#pragma unroll
        for (int j = 0; j < 4; ++j) {
            int c = c4 + j;
            o[j] = (c < IN_DIM) ? (bf16)feat[(size_t)r * IN_DIM + c] : (bf16)0.0f;
        }
        *(bf16x4*)(featbf + (size_t)r * KPAD1 + c4) = o;
        return;
    }
    int w = idx - FEAT_UNITS;
    if (w < R1)                 wt_one(m1aw, Wt1, IN_DIM, KPAD1, w);
    else if (w < R1 + R2)       wt_one(m1bw, Wt2, HID, HID, w - R1);
    else if (w < R1 + 2 * R2)   wt_one(m2aw, Wt3, HID, HID, w - R1 - R2);
    else if (w < R1 + 3 * R2)   wt_one(m2bw, Wt4, HID, HID, w - R1 - 2 * R2);
}

// ---------------------------------------------------------------------------
// colsum8[b&7][c] += partial column sums of feat; 1000 blocks x 192 thr.
__global__ void colsum_feat8(const float* __restrict__ feat, float* __restrict__ colsum8)
{
    int c  = threadIdx.x;
    int r0 = blockIdx.x * 50;
    if (c >= IN_DIM) return;
    float acc = 0.0f;
#pragma unroll 2
    for (int i = 0; i < 50; ++i) {
        int r = r0 + i;
        if (r < N_NODES) acc += feat[(size_t)r * IN_DIM + c];
    }
    atomicAdd(&colsum8[(blockIdx.x & 7) * KPAD1 + c], acc);
}

// ---------------------------------------------------------------------------
// CSR build.
__global__ void degree_hist(const int* __restrict__ dst, int* __restrict__ deg)
{
    int e = blockIdx.x * blockDim.x + threadIdx.x;
    atomicAdd(&deg[dst[e]], 1);
}

__global__ void block_degsum(const int* __restrict__ deg, int* __restrict__ bsum)
{
    __shared__ int s[256];
    int t = threadIdx.x;
    int idx = blockIdx.x * 256 + t;
    int v = (idx < N_NODES) ? deg[idx] : 0;
    s[t] = v;
    __syncthreads();
    for (int off = 128; off > 0; off >>= 1) {
        if (t < off) s[t] += s[t + off];
        __syncthreads();
    }
    if (t == 0) bsum[blockIdx.x] = s[0];
}

// Per-block local scan + self-computed global offset (reads all NB bsums).
__global__ void block_scan_write(const int* __restrict__ deg, const int* __restrict__ bsum,
                                 int* __restrict__ rowptr, int* __restrict__ cursor)
{
    __shared__ int s[256];
    __shared__ int goff;
    int t = threadIdx.x;
    int idx = blockIdx.x * 256 + t;
    // wave 0 computes this block's global offset: sum bsum[0..blockIdx-1]
    if (t < 64) {
        int part = 0;
        for (int i = t; i < blockIdx.x; i += 64) part += bsum[i];
#pragma unroll
        for (int o = 32; o > 0; o >>= 1) part += __shfl_down(part, o, 64);
        if (t == 0) goff = part;
    }
    int v = (idx < N_NODES) ? deg[idx] : 0;
    s[t] = v;
    __syncthreads();
    for (int off = 1; off < 256; off <<= 1) {
        int u = (t >= off) ? s[t - off] : 0;
        __syncthreads();
        s[t] += u;
        __syncthreads();
    }
    int excl = s[t] - v + goff;
    if (idx < N_NODES) {
        rowptr[idx] = excl;
        cursor[idx] = excl;
    }
    if (idx == 0) rowptr[N_NODES] = N_EDGES;
}

__global__ void csr_fill(const int* __restrict__ src, const int* __restrict__ dst,
                         int* __restrict__ cursor, int* __restrict__ csr_src)
{
    int e = blockIdx.x * blockDim.x + threadIdx.x;
    int p = atomicAdd(&cursor[dst[e]], 1);
    csr_src[p] = src[e];
}

// ---------------------------------------------------------------------------
// Gather layer 1: xsum[n][:] = bf16( featbf[n][:] + sum featbf[src][:] )
// Round-7 body: half-wave per src-parity, 16B/lane, 4-row unroll (24 VGPR,
// ~68% occ — 8-deep unroll regressed to 44 VGPR / 41% occ, r9).
__global__ void gather1(const bf16* __restrict__ featbf,
                        const int* __restrict__ rowptr,
                        const int* __restrict__ csr_src,
                        bf16* __restrict__ xsum)
{
    int wave = threadIdx.x >> 6;
    int lane = threadIdx.x & 63;
    int n = blockIdx.x * 4 + wave;
    if (n >= N_NODES) return;
    const int h   = lane >> 5;
    const int cl  = lane & 31;
    const int c   = cl * 8;
    const bool act = (cl < 24);        // 24*8 = 192

    f32x8 acc;
#pragma unroll
    for (int j = 0; j < 8; ++j) acc[j] = 0.0f;
    if (act && h == 0) {
        bf16x8 t0 = *(const bf16x8*)(featbf + (size_t)n * KPAD1 + c);
#pragma unroll
        for (int j = 0; j < 8; ++j) acc[j] = (float)t0[j];
    }

    int je = rowptr[n + 1];
    int jj = rowptr[n] + h;
    for (; jj + 6 < je; jj += 8) {
        int s0 = csr_src[jj], s1 = csr_src[jj + 2];
        int s2 = csr_src[jj + 4], s3 = csr_src[jj + 6];
        if (act) {
            bf16x8 u0 = *(const bf16x8*)(featbf + (size_t)s0 * KPAD1 + c);
            bf16x8 u1 = *(const bf16x8*)(featbf + (size_t)s1 * KPAD1 + c);
            bf16x8 u2 = *(const bf16x8*)(featbf + (size_t)s2 * KPAD1 + c);
            bf16x8 u3 = *(const bf16x8*)(featbf + (size_t)s3 * KPAD1 + c);
#pragma unroll
            for (int j = 0; j < 8; ++j)
                acc[j] += ((float)u0[j] + (float)u1[j]) + ((float)u2[j] + (float)u3[j]);
        }
    }
    for (; jj < je; jj += 2) {
        int s0 = csr_src[jj];
        if (act) {
            bf16x8 u0 = *(const bf16x8*)(featbf + (size_t)s0 * KPAD1 + c);
#pragma unroll
            for (int j = 0; j < 8; ++j) acc[j] += (float)u0[j];
        }
    }

#pragma unroll
    for (int j = 0; j < 8; ++j) acc[j] += __shfl_xor(acc[j], 32, 64);

    if (act && h == 0) {
        bf16x8 o;
#pragma unroll
        for (int j = 0; j < 8; ++j) o[j] = (bf16)acc[j];
        *(bf16x8*)(xsum + (size_t)n * KPAD1 + c) = o;
    }
}

// ---------------------------------------------------------------------------
// Gather layer 2: y2[n][:] = bf16( node1[n][:] + sum node1[src][:] )
// Round-7 body (see gather1 note).
__global__ void gather2(const bf16* __restrict__ node1,
                        const int* __restrict__ rowptr,
                        const int* __restrict__ csr_src,
                        bf16* __restrict__ y2)
{
    int wave = threadIdx.x >> 6;
    int lane = threadIdx.x & 63;
    int n = blockIdx.x * 4 + wave;
    if (n >= N_NODES) return;
    const int h  = lane >> 5;
    const int c  = (lane & 31) * 8;

    f32x8 acc;
    if (h == 0) {
        bf16x8 t0 = *(const bf16x8*)(node1 + (size_t)n * HID + c);
#pragma unroll
        for (int j = 0; j < 8; ++j) acc[j] = (float)t0[j];
    } else {
#pragma unroll
        for (int j = 0; j < 8; ++j) acc[j] = 0.0f;
    }

    int je = rowptr[n + 1];
    int jj = rowptr[n] + h;
    for (; jj + 6 < je; jj += 8) {
        int s0 = csr_src[jj], s1 = csr_src[jj + 2];
        int s2 = csr_src[jj + 4], s3 = csr_src[jj + 6];
        bf16x8 u0 = *(const bf16x8*)(node1 + (size_t)s0 * HID + c);
        bf16x8 u1 = *(const bf16x8*)(node1 + (size_t)s1 * HID + c);
        bf16x8 u2 = *(const bf16x8*)(node1 + (size_t)s2 * HID + c);
        bf16x8 u3 = *(const bf16x8*)(node1 + (size_t)s3 * HID + c);
#pragma unroll
        for (int j = 0; j < 8; ++j)
            acc[j] += ((float)u0[j] + (float)u1[j]) + ((float)u2[j] + (float)u3[j]);
    }
    for (; jj < je; jj += 2) {
        bf16x8 u0 = *(const bf16x8*)(node1 + (size_t)csr_src[jj] * HID + c);
#pragma unroll
        for (int j = 0; j < 8; ++j) acc[j] += (float)u0[j];
    }

#pragma unroll
    for (int j = 0; j < 8; ++j) acc[j] += __shfl_xor(acc[j], 32, 64);

    if (h == 0) {
        bf16x8 o;
#pragma unroll
        for (int j = 0; j < 8; ++j) o[j] = (bf16)acc[j];
        *(bf16x8*)(y2 + (size_t)n * HID + c) = o;
    }
}

// ---------------------------------------------------------------------------
// GEMM v2. Block = 4 waves, tile 128 rows x 256 cols; wave w owns rows
// [w*32,w*32+32) x 256 cols = 8 x mfma_f32_32x32x16_bf16. Wt k-slice staged
// frag-major in LDS via global_load_lds width=16.
// A/B frag: row/col = lane&31, k = (lane>>5)*8 + j
// C/D     : col = lane&31, row = (reg&3) + 8*(reg>>2) + 4*(lane>>5)
template<int KPAD>
__launch_bounds__(256)
__global__ void gemm_relu2(const bf16* __restrict__ X,
                           const bf16* __restrict__ Wt,
                           const float* __restrict__ bias,
                           bf16* __restrict__ out_bf,
                           float* __restrict__ colsum,   // nullable
                           int M)
{
    __shared__ __align__(128) bf16 sB[8192];   // 16 KB
    __shared__ float cs[256];

    const int tid  = threadIdx.x;
    const int w    = tid >> 6;
    const int lane = tid & 63;
    const int p    = lane >> 5;
    const int cn   = lane & 31;
    const int m_base = blockIdx.x * 128 + w * 32;

    int arow = m_base + cn;
    if (arow >= M) arow = M - 1;   // clamp (stores guarded)

    f32x16 acc[8];
#pragma unroll
    for (int j = 0; j < 8; ++j)
#pragma unroll
        for (int r = 0; r < 16; ++r) acc[j][r] = 0.0f;

    for (int k0 = 0; k0 < KPAD; k0 += 32) {
        __syncthreads();
#pragma unroll
        for (int i = 0; i < 4; ++i) {
            int fb = w * 4 + i;
            int j  = fb >> 1;
            int kk = fb & 1;
            const bf16* g = Wt + (size_t)(j * 32 + cn) * KPAD + k0 + kk * 16 + p * 8;
            GLDS16(g, sB + fb * 512);
        }
        __syncthreads();

#pragma unroll
        for (int kk = 0; kk < 2; ++kk) {
            bf16x8 a = *(const bf16x8*)(X + (size_t)arow * KPAD + k0 + kk * 16 + p * 8);
#pragma unroll
            for (int j = 0; j < 8; ++j) {
                bf16x8 b = *(const bf16x8*)(sB + (j * 2 + kk) * 512 + lane * 8);
                acc[j] = __builtin_amdgcn_mfma_f32_32x32x16_bf16(a, b, acc[j], 0, 0, 0);
            }
        }
    }

    if (colsum) {
        cs[tid] = 0.0f;
        __syncthreads();
    }

#pragma unroll
    for (int j = 0; j < 8; ++j) {
        const int col = j * 32 + cn;
        const float bv = bias[col];
        float part = 0.0f;
#pragma unroll
        for (int r = 0; r < 16; ++r) {
            int rl = (r & 3) + 8 * (r >> 2) + 4 * p;
            int mo = m_base + rl;
            if (mo < M) {
                float v = acc[j][r] + bv;
                v = v > 0.0f ? v : 0.0f;
                out_bf[(size_t)mo * HID + col] = (bf16)v;
                part += v;
            }
        }
        if (colsum) {
            part += __shfl_xor(part, 32, 64);   // combine the two p-halves
            if (p == 0) atomicAdd(&cs[col], part);
        }
    }

    if (colsum) {
        __syncthreads();
        atomicAdd(&colsum[tid], cs[tid]);
    }
}

// ---------------------------------------------------------------------------
// Graph head: three GEMVs + sum + final GEMV, single block of 256 threads.
__global__ void graph_head(const float* __restrict__ cs0_8,
                           const float* __restrict__ cs1,
                           const float* __restrict__ cs2,
                           const float* __restrict__ g0w, const float* __restrict__ g0b,
                           const float* __restrict__ g1w, const float* __restrict__ g1b,
                           const float* __restrict__ g2w, const float* __restrict__ g2b,
                           const float* __restrict__ glw, const float* __restrict__ glb,
                           float* __restrict__ gvec)
{
    __shared__ float v0[IN_DIM], v1[HID], v2[HID], gs[HID];
    int t = threadIdx.x;
    if (t < IN_DIM) {
        float s = 0.0f;
#pragma unroll
        for (int i = 0; i < 8; ++i) s += cs0_8[i * KPAD1 + t];
        v0[t] = s;
    }
    v1[t] = cs1[t];
    v2[t] = cs2[t];
    __syncthreads();

    float a0 = 0.0f, a1 = 0.0f, a2 = 0.0f;
    for (int k = 0; k < IN_DIM; ++k) a0 += v0[k] * g0w[k * HID + t];
    for (int k = 0; k < HID; ++k) {
        a1 += v1[k] * g1w[k * HID + t];
        a2 += v2[k] * g2w[k * HID + t];
    }
    float e0 = fmaxf(a0 + g0b[t], 0.0f);
    float e1 = fmaxf(a1 + g1b[t], 0.0f);
    float e2 = fmaxf(a2 + g2b[t], 0.0f);
    gs[t] = e0 + e1 + e2;
    __syncthreads();

    float a3 = 0.0f;
    for (int k = 0; k < HID; ++k) a3 += gs[k] * glw[k * HID + t];
    gvec[t] = fmaxf(a3 + glb[t], 0.0f);
}

// ---------------------------------------------------------------------------
// out[n,c] = node2[n,c](bf16) + gvec[c] (f32 out); 4 elements per thread.
__global__ void final_add(const bf16* __restrict__ node2,
                          const float* __restrict__ gvec,
                          float* __restrict__ out)
{
    int idx = blockIdx.x * blockDim.x + threadIdx.x;
    size_t base = (size_t)idx * 4;
    int c = (int)(base & (HID - 1));
    bf16x4 v = *(const bf16x4*)(node2 + base);
    f32x4 g = *(const f32x4*)(gvec + c);
    f32x4 o;
#pragma unroll
    for (int j = 0; j < 4; ++j) o[j] = (float)v[j] + g[j];
    *(f32x4*)(out + base) = o;
}

// ---------------------------------------------------------------------------
extern "C" void kernel_launch(void* const* d_in, const int* in_sizes, int n_in,
                              void* d_out, int out_size, void* d_ws, size_t ws_size,
                              hipStream_t stream)
{
    const float* feat = (const float*)d_in[0];
    const int*   ei   = (const int*)d_in[1];
    const int*   src  = ei;
    const int*   dst  = ei + N_EDGES;
    const float* g0w = (const float*)d_in[2],  *g0b = (const float*)d_in[3];
    const float* g1w = (const float*)d_in[4],  *g1b = (const float*)d_in[5];
    const float* g2w = (const float*)d_in[6],  *g2b = (const float*)d_in[7];
    const float* glw = (const float*)d_in[8],  *glb = (const float*)d_in[9];
    const float* m1aw = (const float*)d_in[10], *m1ab = (const float*)d_in[11];
    const float* m1bw = (const float*)d_in[12], *m1bb = (const float*)d_in[13];
    const float* m2aw = (const float*)d_in[14], *m2ab = (const float*)d_in[15];
    const float* m2bw = (const float*)d_in[16], *m2bb = (const float*)d_in[17];
    float* out = (float*)d_out;

    char* ws = (char*)d_ws;
    size_t off = 0;
    auto alloc = [&](size_t bytes) -> void* {
        void* p = ws + off;
        off += (bytes + 255) & ~(size_t)255;
        return p;
    };
    bf16*  featbf = (bf16*)alloc((size_t)N_NODES * KPAD1 * 2);
    bf16*  xsum  = (bf16*) alloc((size_t)N_NODES * KPAD1 * 2);
    bf16*  y2    = (bf16*) alloc((size_t)N_NODES * HID * 2);
    bf16*  node2 = (bf16*) alloc((size_t)N_NODES * HID * 2);
    bf16*  h1    = (bf16*) alloc((size_t)N_NODES * HID * 2);   // reused as h2
    bf16*  node1 = (bf16*) alloc((size_t)N_NODES * HID * 2);
    bf16*  Wt1   = (bf16*) alloc((size_t)HID * KPAD1 * 2);
    bf16*  Wt2   = (bf16*) alloc((size_t)HID * HID * 2);
    bf16*  Wt3   = (bf16*) alloc((size_t)HID * HID * 2);
    bf16*  Wt4   = (bf16*) alloc((size_t)HID * HID * 2);
    int*   deg     = (int*)alloc((size_t)N_NODES * 4);
    int*   rowptr  = (int*)alloc((size_t)(N_NODES + 1) * 4);
    int*   cursor  = (int*)alloc((size_t)N_NODES * 4);
    int*   csr_src = (int*)alloc((size_t)N_EDGES * 4);
    int*   bsum    = (int*)alloc(256 * 4);
    float* csums   = (float*)alloc((8 * KPAD1 + 256 + 256 + 256) * 4);
    float* colsum0_8 = csums;                    // 8 x 192 partial slots
    float* colsum1   = csums + 8 * KPAD1;        // 256
    float* colsum2   = csums + 8 * KPAD1 + 256;  // 256
    float* gvec      = csums + 8 * KPAD1 + 512;  // 256

    hipMemsetAsync(csums, 0, (8 * KPAD1 + 512) * 4, stream);
    hipMemsetAsync(deg, 0, (size_t)N_NODES * 4, stream);

    // fused feat->bf16 + all weight transposes
    prep_kernel<<<(FEAT_UNITS + R1 + 3 * R2 + 255) / 256, 256, 0, stream>>>(
        feat, featbf, m1aw, m1bw, m2aw, m2bw, Wt1, Wt2, Wt3, Wt4);
    // colsum0 partials (8-slot spread)
    colsum_feat8<<<1000, 192, 0, stream>>>(feat, colsum0_8);

    // CSR build (grouped by dst) — scan_bsum folded into block_scan_write
    degree_hist<<<N_EDGES / 256, 256, 0, stream>>>(dst, deg);
    block_degsum<<<NB, 256, 0, stream>>>(deg, bsum);
    block_scan_write<<<NB, 256, 0, stream>>>(deg, bsum, rowptr, cursor);
    csr_fill<<<N_EDGES / 256, 256, 0, stream>>>(src, dst, cursor, csr_src);

    // xsum = bf16(feat + gather(feat))
    gather1<<<(N_NODES + 3) / 4, 256, 0, stream>>>(featbf, rowptr, csr_src, xsum);

    const int gblocks = (N_NODES + 127) / 128;
    // h1 = relu(xsum @ m1a_w + b)
    gemm_relu2<KPAD1><<<gblocks, 256, 0, stream>>>(xsum, Wt1, m1ab, h1, nullptr, N_NODES);
    // node1 = relu(h1 @ m1b_w + b), colsum1 fused
    gemm_relu2<HID><<<gblocks, 256, 0, stream>>>(h1, Wt2, m1bb, node1, colsum1, N_NODES);
    // y2 = bf16(node1 + gather(node1))
    gather2<<<(N_NODES + 3) / 4, 256, 0, stream>>>(node1, rowptr, csr_src, y2);
    // h2 = relu(y2 @ m2a_w + b)  (reuse h1 buffer)
    gemm_relu2<HID><<<gblocks, 256, 0, stream>>>(y2, Wt3, m2ab, h1, nullptr, N_NODES);
    // node2 = relu(h2 @ m2b_w + b), colsum2 fused
    gemm_relu2<HID><<<gblocks, 256, 0, stream>>>(h1, Wt4, m2bb, node2, colsum2, N_NODES);
    // graph head -> gvec = g_last
    graph_head<<<1, 256, 0, stream>>>(colsum0_8, colsum1, colsum2,
                                      g0w, g0b, g1w, g1b, g2w, g2b, glw, glb, gvec);
    // out = node2 + gvec
    final_add<<<((size_t)N_NODES * HID / 4 + 255) / 256, 256, 0, stream>>>(node2, gvec, out);
    (void)in_sizes; (void)n_in; (void)out_size; (void)ws_size;
}